// Round 4
// baseline (392.654 us; speedup 1.0000x reference)
//
#include <hip/hip_runtime.h>

typedef unsigned short u16;
typedef unsigned int u32;
typedef unsigned char u8;
typedef unsigned long long u64;
typedef __attribute__((ext_vector_type(8))) short short8;
typedef __attribute__((ext_vector_type(4))) float f32x4;
typedef __attribute__((ext_vector_type(8))) int i32x8;

// ---------- helpers ----------
__device__ inline u16 f2bf(float f) {           // RNE fp32->bf16
  u32 x = __float_as_uint(f);
  x += 0x7fff + ((x >> 16) & 1);
  return (u16)(x >> 16);
}
__device__ inline float bf2f(u16 h) {
  return __uint_as_float(((u32)h) << 16);
}
// RNE fp32 -> OCP e4m3fn; flush |f| < 2^-6 to 0 (values here are < 8, no sat needed)
__device__ inline u8 f2e4m3(float f) {
  u32 x = __float_as_uint(f);
  u32 s = (x >> 24) & 0x80;
  u32 a = x & 0x7fffffff;
  u32 rnd = a + 0x7ffff + ((a >> 20) & 1);
  u32 e = (rnd >> 23) - 120;           // (exp-127)+7
  u32 m = (rnd >> 20) & 7;
  u8 v = (u8)(s | (e << 3) | m);
  return (a < 0x3c800000) ? (u8)s : v;
}
__device__ inline void gload16(const void* g, void* l) {
  __builtin_amdgcn_global_load_lds((const __attribute__((address_space(1))) u32*)g,
                                   (__attribute__((address_space(3))) u32*)l, 16, 0, 0);
}
__device__ inline i32x8 ld_frag32(const char* p) {  // 32B LDS read as two b128
  const int4 lo = *(const int4*)p;
  const int4 hi = *(const int4*)(p + 16);
  i32x8 f;
  f[0] = lo.x; f[1] = lo.y; f[2] = lo.z; f[3] = lo.w;
  f[4] = hi.x; f[5] = hi.y; f[6] = hi.z; f[7] = hi.w;
  return f;
}

// swizzled 128x128 bf16 epilogue tile: 16B granules XORed so column reads spread banks
__device__ inline int stile_off(int rg, int cg) {
  return rg * 128 + ((((cg >> 3) ^ ((rg >> 3) & 7)) << 3)) + (cg & 7);
}

// ---------- fused cast fp32 -> bf16 for embd and W ----------
__global__ void cast_all(const float* __restrict__ embd, const float* __restrict__ W,
                         u16* __restrict__ embd_b, u16* __restrict__ W_b) {
  const float* src; u16* dst; size_t i;
  if (blockIdx.x < 16384) {
    src = embd; dst = embd_b;
    i = ((size_t)blockIdx.x * 256 + threadIdx.x) * 4;
  } else {
    src = W; dst = W_b;
    i = ((size_t)(blockIdx.x - 16384) * 256 + threadIdx.x) * 4;
  }
  float4 v = *(const float4*)(src + i);
  ushort4 o;
  o.x = f2bf(v.x); o.y = f2bf(v.y); o.z = f2bf(v.z); o.w = f2bf(v.w);
  *(ushort4*)(dst + i) = o;
}

// ============================================================================
// Kernel 1: c = embd @ W^T + b. Writes cT (bf16 [o][n] per batch) and c8 (fp8
// e4m3 row-major [n][o]). bf16 row-major c is dead -> not written.
// grid (stripe=8, 128): XCD = m-stripe (2048 rows of embd = 4 MB, L2-resident)
// ============================================================================
__global__ __launch_bounds__(256, 2)
void gemm_linear(const u16* __restrict__ A, const u16* __restrict__ B,
                 u16* __restrict__ CT, u8* __restrict__ C8,
                 const float* __restrict__ bias)
{
  __shared__ __align__(16) char smem[32768];
  u16* As = (u16*)smem;            // 128*32 bf16
  u16* Bs = As + 128 * 32;
  u16* stile = (u16*)smem;         // 128x128 swizzled bf16 (epilogue)

  const int K = 1024, N = 1024;
  const int mBase = blockIdx.x * 2048 + (blockIdx.y >> 3) * 128;
  const int nBase = (blockIdx.y & 7) * 128;

  const int tid  = threadIdx.x;
  const int lane = tid & 63;
  const int wave = tid >> 6;
  const int wm = (wave >> 1) * 64;
  const int wn = (wave & 1) * 64;
  const int q = lane >> 4;
  const int r = lane & 15;

  const int lo0 = tid * 16;
  const int lo1 = lo0 + 4096;
  const int row0 = lo0 >> 6, kc0 = (lo0 & 63) >> 1;
  const int row1 = lo1 >> 6, kc1 = (lo1 & 63) >> 1;

  const u16* a0 = A + (size_t)(mBase + row0) * K + kc0;
  const u16* a1 = A + (size_t)(mBase + row1) * K + kc1;
  const u16* b0 = B + (size_t)(nBase + row0) * K + kc0;
  const u16* b1 = B + (size_t)(nBase + row1) * K + kc1;

  f32x4 acc[4][4] = {};

  for (int k0 = 0; k0 < K; k0 += 32) {
    gload16(a0 + k0, (char*)As + lo0);
    gload16(a1 + k0, (char*)As + lo1);
    gload16(b0 + k0, (char*)Bs + lo0);
    gload16(b1 + k0, (char*)Bs + lo1);
    __syncthreads();
    short8 af[4], bfr[4];
#pragma unroll
    for (int t = 0; t < 4; ++t) {
      af[t]  = *(const short8*)(As + (wm + t * 16 + r) * 32 + q * 8);
      bfr[t] = *(const short8*)(Bs + (wn + t * 16 + r) * 32 + q * 8);
    }
#pragma unroll
    for (int mi = 0; mi < 4; ++mi)
#pragma unroll
      for (int ni = 0; ni < 4; ++ni)
        acc[mi][ni] = __builtin_amdgcn_mfma_f32_16x16x32_bf16(af[mi], bfr[ni], acc[mi][ni], 0, 0, 0);
    __syncthreads();
  }

  // epilogue: stash to swizzled LDS tile (C/D: col=r, row=q*4+reg)
  float bv[4];
#pragma unroll
  for (int ni = 0; ni < 4; ++ni) bv[ni] = bias[nBase + wn + ni * 16 + r];
#pragma unroll
  for (int mi = 0; mi < 4; ++mi)
#pragma unroll
    for (int ni = 0; ni < 4; ++ni)
#pragma unroll
      for (int reg = 0; reg < 4; ++reg)
        stile[stile_off(wm + mi * 16 + q * 4 + reg, wn + ni * 16 + r)] =
            f2bf(acc[mi][ni][reg] + bv[ni]);
  __syncthreads();

  const int z1 = mBase >> 11;             // batch
  const int n0 = mBase & 2047;
  u16* ctb = CT + (size_t)z1 * 1024 * 2048;

  // c8 write: row reads, convert bf16->e4m3, coalesced 8B stores
#pragma unroll
  for (int rnd = 0; rnd < 8; ++rnd) {
    int idx = rnd * 256 + tid;
    int ch = idx & 15, n = idx >> 4;
    short8 v = *(const short8*)(stile + n * 128 + ((ch ^ ((n >> 3) & 7)) << 3));
    union { u64 q8; u8 b[8]; } u;
#pragma unroll
    for (int j = 0; j < 8; ++j) u.b[j] = f2e4m3(bf2f((u16)v[j]));
    *(u64*)(C8 + (size_t)(mBase + n) * N + nBase + ch * 8) = u.q8;
  }
  // cT write: column reads (swizzle-spread), coalesced 16B stores
#pragma unroll
  for (int rnd = 0; rnd < 8; ++rnd) {
    int idx = rnd * 256 + tid;
    int ch = idx & 15, cc = idx >> 4;
    short8 v;
#pragma unroll
    for (int j = 0; j < 8; ++j) v[j] = (short)stile[stile_off(ch * 8 + j, cc)];
    *(short8*)(ctb + (size_t)(nBase + cc) * 2048 + n0 + ch * 8) = v;
  }
}

// ============================================================================
// Kernel 2: scores. S = c8 . c8^T / 32 (MX-fp8 MFMA, scale=1), P = exp(S) bf16
// (unnormalized, symmetric: triangular grid, mirrored writes), atomic rowsums.
// grid (batch=8, pair=136). BK=128, 16x16x128 f8f6f4, const scale 0x7f (=2^0).
// LDS A/B tiles: 128 rows x 128B, 32B granules XOR-swizzled (pos = g ^ (row&3))
// via inverse swizzle on the GLOBAL side (global_load_lds is lane*16-rigid).
// ============================================================================
__global__ __launch_bounds__(256, 2)
void gemm_scores_fp8(const u8* __restrict__ C8, u16* __restrict__ P,
                     float* __restrict__ rowsum)
{
  __shared__ __align__(16) char smem[32768];
  char* As8 = smem;                // 16 KB
  char* Bs8 = smem + 16384;        // 16 KB
  u16* stile = (u16*)smem;         // epilogue union

  const int z = blockIdx.x;
  C8 += (size_t)z * 2048 * 1024;
  P += (size_t)z * 2048 * 2048;
  rowsum += (size_t)z * 2048;

  int t = blockIdx.y, row_ = 0;
  while (t >= 16 - row_) { t -= 16 - row_; ++row_; }
  const int bi = row_, bj = row_ + t;
  const int mBase = bi * 128, nBase = bj * 128;

  const int tid  = threadIdx.x;
  const int lane = tid & 63;
  const int wave = tid >> 6;
  const int wm = (wave >> 1) * 64;
  const int wn = (wave & 1) * 64;
  const int q = lane >> 4;
  const int r = lane & 15;

  // staging: 4 issues of 4KB per tile; lane -> (row, swizzled granule)
  const int rl = tid >> 3;                         // 0..31 rows per issue
  const int Cg = ((tid & 7) >> 1) ^ (rl & 3);      // content granule (inverse swizzle)
  const int kb = Cg * 32 + (tid & 1) * 16;         // content k-byte
  const u8* aP = C8 + (size_t)(mBase + rl) * 1024 + kb;
  const u8* bP = C8 + (size_t)(nBase + rl) * 1024 + kb;
  const int ldst = tid * 16;

  f32x4 acc[4][4] = {};

  for (int k0 = 0; k0 < 1024; k0 += 128) {
#pragma unroll
    for (int j = 0; j < 4; ++j) {
      gload16(aP + j * 32768 + k0, As8 + j * 4096 + ldst);
      gload16(bP + j * 32768 + k0, Bs8 + j * 4096 + ldst);
    }
    __syncthreads();
    i32x8 af[4], bfz[4];
#pragma unroll
    for (int tt = 0; tt < 4; ++tt) {
      int rowa = wm + tt * 16 + r;
      af[tt]  = ld_frag32(As8 + rowa * 128 + ((q ^ (rowa & 3)) << 5));
      int rowb = wn + tt * 16 + r;
      bfz[tt] = ld_frag32(Bs8 + rowb * 128 + ((q ^ (rowb & 3)) << 5));
    }
#pragma unroll
    for (int mi = 0; mi < 4; ++mi)
#pragma unroll
      for (int ni = 0; ni < 4; ++ni)
        acc[mi][ni] = __builtin_amdgcn_mfma_scale_f32_16x16x128_f8f6f4(
            af[mi], bfz[ni], acc[mi][ni], 0, 0, 0, 0x7f7f7f7f, 0, 0x7f7f7f7f);
    __syncthreads();
  }

  // epilogue: exp(acc/32), bf16 tile + mirror, rowsums (direct + colsums)
  const float scale = 0.03125f;
  const bool mirror = (bi != bj);
  float colacc[4] = {0.f, 0.f, 0.f, 0.f};
#pragma unroll
  for (int mi = 0; mi < 4; ++mi) {
    float rs[4] = {0.f, 0.f, 0.f, 0.f};
#pragma unroll
    for (int ni = 0; ni < 4; ++ni)
#pragma unroll
      for (int reg = 0; reg < 4; ++reg) {
        float e = __expf(acc[mi][ni][reg] * scale);
        u16 h = f2bf(e);
        float f = bf2f(h);
        rs[reg] += f;
        if (mirror) colacc[ni] += f;
        stile[stile_off(wm + mi * 16 + q * 4 + reg, wn + ni * 16 + r)] = h;
      }
#pragma unroll
    for (int reg = 0; reg < 4; ++reg) {
      float v = rs[reg];
      v += __shfl_xor(v, 1);
      v += __shfl_xor(v, 2);
      v += __shfl_xor(v, 4);
      v += __shfl_xor(v, 8);
      if (r == 0)
        atomicAdd(&rowsum[mBase + wm + mi * 16 + q * 4 + reg], v);
    }
  }
  if (mirror) {
#pragma unroll
    for (int ni = 0; ni < 4; ++ni) {
      float v = colacc[ni];
      v += __shfl_xor(v, 16);
      v += __shfl_xor(v, 32);
      if (q == 0)
        atomicAdd(&rowsum[nBase + wn + ni * 16 + r], v);
    }
  }
  __syncthreads();
#pragma unroll
  for (int rnd = 0; rnd < 8; ++rnd) {
    int idx = rnd * 256 + tid;
    int ch = idx & 15, n = idx >> 4;
    short8 v = *(const short8*)(stile + n * 128 + ((ch ^ ((n >> 3) & 7)) << 3));
    *(short8*)(P + (size_t)(mBase + n) * 2048 + nBase + ch * 8) = v;
  }
  if (mirror) {
#pragma unroll
    for (int rnd = 0; rnd < 8; ++rnd) {
      int idx = rnd * 256 + tid;
      int ch = idx & 15, cc = idx >> 4;
      short8 v;
#pragma unroll
      for (int j = 0; j < 8; ++j) v[j] = (short)stile[stile_off(ch * 8 + j, cc)];
      *(short8*)(P + (size_t)(nBase + cc) * 2048 + mBase + ch * 8) = v;
    }
  }
}

// ============================================================================
// Kernel 3: O = (P @ c) / rowsum. A=P bf16 (K=2048), B=cT bf16, fp32 out.
// grid (batch=8, mblk*8+nblk=128): XCD = batch, n-fastest.
// ============================================================================
__global__ __launch_bounds__(256, 2)
void gemm_pv(const u16* __restrict__ A, const u16* __restrict__ B,
             float* __restrict__ Cf, const float* __restrict__ rowsum)
{
  __shared__ __align__(16) char smem[32768];
  u16* As = (u16*)smem;
  u16* Bs = As + 128 * 32;
  float* stf = (float*)smem;       // 64x128 f32 epilogue staging

  const int K = 2048, N = 1024;
  const int z = blockIdx.x;
  A += (size_t)z * 2048 * 2048;
  B += (size_t)z * 1024 * 2048;
  Cf += (size_t)z * 2048 * 1024;
  rowsum += (size_t)z * 2048;

  const int nBase = (blockIdx.y & 7) * 128;
  const int mBase = (blockIdx.y >> 3) * 128;

  const int tid  = threadIdx.x;
  const int lane = tid & 63;
  const int wave = tid >> 6;
  const int wm = (wave >> 1) * 64;
  const int wn = (wave & 1) * 64;
  const int q = lane >> 4;
  const int r = lane & 15;

  const int lo0 = tid * 16;
  const int lo1 = lo0 + 4096;
  const int row0 = lo0 >> 6, kc0 = (lo0 & 63) >> 1;
  const int row1 = lo1 >> 6, kc1 = (lo1 & 63) >> 1;

  const u16* a0 = A + (size_t)(mBase + row0) * K + kc0;
  const u16* a1 = A + (size_t)(mBase + row1) * K + kc1;
  const u16* b0 = B + (size_t)(nBase + row0) * K + kc0;
  const u16* b1 = B + (size_t)(nBase + row1) * K + kc1;

  f32x4 acc[4][4] = {};

  for (int k0 = 0; k0 < K; k0 += 32) {
    gload16(a0 + k0, (char*)As + lo0);
    gload16(a1 + k0, (char*)As + lo1);
    gload16(b0 + k0, (char*)Bs + lo0);
    gload16(b1 + k0, (char*)Bs + lo1);
    __syncthreads();
    short8 af[4], bfr[4];
#pragma unroll
    for (int t = 0; t < 4; ++t) {
      af[t]  = *(const short8*)(As + (wm + t * 16 + r) * 32 + q * 8);
      bfr[t] = *(const short8*)(Bs + (wn + t * 16 + r) * 32 + q * 8);
    }
#pragma unroll
    for (int mi = 0; mi < 4; ++mi)
#pragma unroll
      for (int ni = 0; ni < 4; ++ni)
        acc[mi][ni] = __builtin_amdgcn_mfma_f32_16x16x32_bf16(af[mi], bfr[ni], acc[mi][ni], 0, 0, 0);
    __syncthreads();
  }

  // normalize + fp32 store, staged through LDS in two 64-row phases
#pragma unroll
  for (int p = 0; p < 2; ++p) {
    if ((wave >> 1) == p) {
#pragma unroll
      for (int mi = 0; mi < 4; ++mi)
#pragma unroll
        for (int reg = 0; reg < 4; ++reg) {
          int lr = mi * 16 + q * 4 + reg;
          float inv = 1.0f / rowsum[mBase + wm + lr];
#pragma unroll
          for (int ni = 0; ni < 4; ++ni)
            stf[lr * 128 + wn + ni * 16 + r] = acc[mi][ni][reg] * inv;
        }
    }
    __syncthreads();
#pragma unroll
    for (int rnd = 0; rnd < 8; ++rnd) {
      int idx = rnd * 256 + tid;
      int n = idx >> 5, ch = idx & 31;
      float4 v = *(const float4*)(stf + n * 128 + ch * 4);
      *(float4*)(Cf + (size_t)(mBase + p * 64 + n) * N + nBase + ch * 4) = v;
    }
    __syncthreads();
  }
}

// ---------- launch ----------
// B=8, N=2048, E=O=1024
extern "C" void kernel_launch(void* const* d_in, const int* in_sizes, int n_in,
                              void* d_out, int out_size, void* d_ws, size_t ws_size,
                              hipStream_t stream) {
  const float* embd = (const float*)d_in[0];
  const float* W    = (const float*)d_in[1];
  const float* bias = (const float*)d_in[2];
  float* out = (float*)d_out;

  char* ws = (char*)d_ws;
  // lifetimes: cast -> linear -> scores -> pv
  u16* cT_b   = (u16*)(ws);                         // [0,32M)   W:linear R:pv
  u16* P_b    = (u16*)(ws + (32ull << 20));         // [32,96M)  W:scores R:pv
  u16* embd_b = (u16*)(ws + (32ull << 20));         // [32,64M)  alias P (dead before scores)
  u16* W_b    = (u16*)(ws + (64ull << 20));         // [64,66M)  alias P (dead before scores)
  u8*  c8     = (u8*)(ws + (96ull << 20));          // [96,112M) W:linear R:scores
  float* rowsum = (float*)(ws + (112ull << 20));    // 64 KB

  cast_all<<<17408, 256, 0, stream>>>(embd, W, embd_b, W_b);

  gemm_linear<<<dim3(8, 128, 1), 256, 0, stream>>>(embd_b, W_b, cT_b, c8, bias);

  hipMemsetAsync(rowsum, 0, 16384 * sizeof(float), stream);

  gemm_scores_fp8<<<dim3(8, 136, 1), 256, 0, stream>>>(c8, P_b, rowsum);

  gemm_pv<<<dim3(8, 128, 1), 256, 0, stream>>>(P_b, cT_b, out, rowsum);
}

// Round 5
// 392.459 us; speedup vs baseline: 1.0005x; 1.0005x over previous
//
#include <hip/hip_runtime.h>

typedef unsigned short u16;
typedef unsigned int u32;
typedef unsigned char u8;
typedef unsigned long long u64;
typedef __attribute__((ext_vector_type(8))) short short8;
typedef __attribute__((ext_vector_type(4))) float f32x4;
typedef __attribute__((ext_vector_type(8))) int i32x8;

// ---------- helpers ----------
__device__ inline u16 f2bf(float f) {           // RNE fp32->bf16
  u32 x = __float_as_uint(f);
  x += 0x7fff + ((x >> 16) & 1);
  return (u16)(x >> 16);
}
__device__ inline float bf2f(u16 h) {
  return __uint_as_float(((u32)h) << 16);
}
// RNE fp32 -> OCP e4m3fn; flush |f| < 2^-6 to 0 (values here are < 8, no sat needed)
__device__ inline u8 f2e4m3(float f) {
  u32 x = __float_as_uint(f);
  u32 s = (x >> 24) & 0x80;
  u32 a = x & 0x7fffffff;
  u32 rnd = a + 0x7ffff + ((a >> 20) & 1);
  u32 e = (rnd >> 23) - 120;           // (exp-127)+7
  u32 m = (rnd >> 20) & 7;
  u8 v = (u8)(s | (e << 3) | m);
  return (a < 0x3c800000) ? (u8)s : v;
}
__device__ inline void gload16(const void* g, void* l) {
  __builtin_amdgcn_global_load_lds((const __attribute__((address_space(1))) u32*)g,
                                   (__attribute__((address_space(3))) u32*)l, 16, 0, 0);
}
__device__ inline i32x8 ld_frag32(const char* p) {  // 32B LDS read as two b128
  const int4 lo = *(const int4*)p;
  const int4 hi = *(const int4*)(p + 16);
  i32x8 f;
  f[0] = lo.x; f[1] = lo.y; f[2] = lo.z; f[3] = lo.w;
  f[4] = hi.x; f[5] = hi.y; f[6] = hi.z; f[7] = hi.w;
  return f;
}

// swizzled 128x128 bf16 epilogue tile: 16B granules XORed so column reads spread banks
__device__ inline int stile_off(int rg, int cg) {
  return rg * 128 + ((((cg >> 3) ^ ((rg >> 3) & 7)) << 3)) + (cg & 7);
}

// ---------- fused cast fp32 -> bf16 for embd and W ----------
__global__ void cast_all(const float* __restrict__ embd, const float* __restrict__ W,
                         u16* __restrict__ embd_b, u16* __restrict__ W_b) {
  const float* src; u16* dst; size_t i;
  if (blockIdx.x < 16384) {
    src = embd; dst = embd_b;
    i = ((size_t)blockIdx.x * 256 + threadIdx.x) * 4;
  } else {
    src = W; dst = W_b;
    i = ((size_t)(blockIdx.x - 16384) * 256 + threadIdx.x) * 4;
  }
  float4 v = *(const float4*)(src + i);
  ushort4 o;
  o.x = f2bf(v.x); o.y = f2bf(v.y); o.z = f2bf(v.z); o.w = f2bf(v.w);
  *(ushort4*)(dst + i) = o;
}

// ============================================================================
// Kernel 1: c = embd @ W^T + b. Writes cT (bf16 [o][n] per batch) and c8 (fp8
// e4m3 row-major [n][o]). bf16 row-major c is dead -> not written.
// grid (stripe=8, 128): XCD = m-stripe (2048 rows of embd = 4 MB, L2-resident)
// ============================================================================
__global__ __launch_bounds__(256, 2)
void gemm_linear(const u16* __restrict__ A, const u16* __restrict__ B,
                 u16* __restrict__ CT, u8* __restrict__ C8,
                 const float* __restrict__ bias)
{
  __shared__ __align__(16) char smem[32768];
  u16* As = (u16*)smem;            // 128*32 bf16
  u16* Bs = As + 128 * 32;
  u16* stile = (u16*)smem;         // 128x128 swizzled bf16 (epilogue)

  const int K = 1024, N = 1024;
  const int mBase = blockIdx.x * 2048 + (blockIdx.y >> 3) * 128;
  const int nBase = (blockIdx.y & 7) * 128;

  const int tid  = threadIdx.x;
  const int lane = tid & 63;
  const int wave = tid >> 6;
  const int wm = (wave >> 1) * 64;
  const int wn = (wave & 1) * 64;
  const int q = lane >> 4;
  const int r = lane & 15;

  const int lo0 = tid * 16;
  const int lo1 = lo0 + 4096;
  const int row0 = lo0 >> 6, kc0 = (lo0 & 63) >> 1;
  const int row1 = lo1 >> 6, kc1 = (lo1 & 63) >> 1;

  const u16* a0 = A + (size_t)(mBase + row0) * K + kc0;
  const u16* a1 = A + (size_t)(mBase + row1) * K + kc1;
  const u16* b0 = B + (size_t)(nBase + row0) * K + kc0;
  const u16* b1 = B + (size_t)(nBase + row1) * K + kc1;

  f32x4 acc[4][4] = {};

  for (int k0 = 0; k0 < K; k0 += 32) {
    gload16(a0 + k0, (char*)As + lo0);
    gload16(a1 + k0, (char*)As + lo1);
    gload16(b0 + k0, (char*)Bs + lo0);
    gload16(b1 + k0, (char*)Bs + lo1);
    __syncthreads();
    short8 af[4], bfr[4];
#pragma unroll
    for (int t = 0; t < 4; ++t) {
      af[t]  = *(const short8*)(As + (wm + t * 16 + r) * 32 + q * 8);
      bfr[t] = *(const short8*)(Bs + (wn + t * 16 + r) * 32 + q * 8);
    }
#pragma unroll
    for (int mi = 0; mi < 4; ++mi)
#pragma unroll
      for (int ni = 0; ni < 4; ++ni)
        acc[mi][ni] = __builtin_amdgcn_mfma_f32_16x16x32_bf16(af[mi], bfr[ni], acc[mi][ni], 0, 0, 0);
    __syncthreads();
  }

  // epilogue: stash to swizzled LDS tile (C/D: col=r, row=q*4+reg)
  float bv[4];
#pragma unroll
  for (int ni = 0; ni < 4; ++ni) bv[ni] = bias[nBase + wn + ni * 16 + r];
#pragma unroll
  for (int mi = 0; mi < 4; ++mi)
#pragma unroll
    for (int ni = 0; ni < 4; ++ni)
#pragma unroll
      for (int reg = 0; reg < 4; ++reg)
        stile[stile_off(wm + mi * 16 + q * 4 + reg, wn + ni * 16 + r)] =
            f2bf(acc[mi][ni][reg] + bv[ni]);
  __syncthreads();

  const int z1 = mBase >> 11;             // batch
  const int n0 = mBase & 2047;
  u16* ctb = CT + (size_t)z1 * 1024 * 2048;

  // c8 write: row reads, convert bf16->e4m3, coalesced 8B stores
#pragma unroll
  for (int rnd = 0; rnd < 8; ++rnd) {
    int idx = rnd * 256 + tid;
    int ch = idx & 15, n = idx >> 4;
    short8 v = *(const short8*)(stile + n * 128 + ((ch ^ ((n >> 3) & 7)) << 3));
    union { u64 q8; u8 b[8]; } u;
#pragma unroll
    for (int j = 0; j < 8; ++j) u.b[j] = f2e4m3(bf2f((u16)v[j]));
    *(u64*)(C8 + (size_t)(mBase + n) * N + nBase + ch * 8) = u.q8;
  }
  // cT write: column reads (swizzle-spread), coalesced 16B stores
#pragma unroll
  for (int rnd = 0; rnd < 8; ++rnd) {
    int idx = rnd * 256 + tid;
    int ch = idx & 15, cc = idx >> 4;
    short8 v;
#pragma unroll
    for (int j = 0; j < 8; ++j) v[j] = (short)stile[stile_off(ch * 8 + j, cc)];
    *(short8*)(ctb + (size_t)(nBase + cc) * 2048 + n0 + ch * 8) = v;
  }
}

// ============================================================================
// Kernel 2: scores. S = c8 . c8^T / 32 (MX-fp8 MFMA, scale=1), P = exp(S) bf16
// (unnormalized, symmetric: triangular grid, mirrored writes), atomic rowsums.
// grid (batch=8, pair=136). BK=128, 16x16x128 f8f6f4, const scale 0x7f (=2^0).
// LDS A/B tiles: 128 rows x 128B, 32B granules XOR-swizzled (pos = g ^ (row&3))
// via inverse swizzle on the GLOBAL side (global_load_lds is lane*16-rigid).
// REGISTER BUDGET (R4 spilled at 128-cap): acc 64 + af[4] 32 + ONE live bfz 8
// + addressing ~15 ≈ 119 < 128. ni-outer loop keeps a single bfz live.
// ============================================================================
__global__ __launch_bounds__(256, 2)
void gemm_scores_fp8(const u8* __restrict__ C8, u16* __restrict__ P,
                     float* __restrict__ rowsum)
{
  __shared__ __align__(16) char smem[32768];
  char* As8 = smem;                // 16 KB
  char* Bs8 = smem + 16384;        // 16 KB
  u16* stile = (u16*)smem;         // epilogue union

  const int z = blockIdx.x;
  C8 += (size_t)z * 2048 * 1024;
  P += (size_t)z * 2048 * 2048;
  rowsum += (size_t)z * 2048;

  int t = blockIdx.y, row_ = 0;
  while (t >= 16 - row_) { t -= 16 - row_; ++row_; }
  const int bi = row_, bj = row_ + t;
  const int mBase = bi * 128, nBase = bj * 128;

  const int tid  = threadIdx.x;
  const int lane = tid & 63;
  const int wave = tid >> 6;
  const int wm = (wave >> 1) * 64;
  const int wn = (wave & 1) * 64;
  const int q = lane >> 4;
  const int r = lane & 15;

  // staging: 4 issues of 4KB per tile; lane -> (row, swizzled granule)
  const int rl = tid >> 3;                         // 0..31 rows per issue
  const int Cg = ((tid & 7) >> 1) ^ (rl & 3);      // content granule (inverse swizzle)
  const int kb = Cg * 32 + (tid & 1) * 16;         // content k-byte
  const u8* aP = C8 + (size_t)(mBase + rl) * 1024 + kb;
  const u8* bP = C8 + (size_t)(nBase + rl) * 1024 + kb;
  const int ldst = tid * 16;

  f32x4 acc[4][4] = {};

  for (int k0 = 0; k0 < 1024; k0 += 128) {
#pragma unroll
    for (int j = 0; j < 4; ++j) {
      gload16(aP + j * 32768 + k0, As8 + j * 4096 + ldst);
      gload16(bP + j * 32768 + k0, Bs8 + j * 4096 + ldst);
    }
    __syncthreads();
    i32x8 af[4];
#pragma unroll
    for (int tt = 0; tt < 4; ++tt) {
      int rowa = wm + tt * 16 + r;
      af[tt] = ld_frag32(As8 + rowa * 128 + ((q ^ (rowa & 3)) << 5));
    }
#pragma unroll
    for (int ni = 0; ni < 4; ++ni) {
      int rowb = wn + ni * 16 + r;
      i32x8 bfz = ld_frag32(Bs8 + rowb * 128 + ((q ^ (rowb & 3)) << 5));
#pragma unroll
      for (int mi = 0; mi < 4; ++mi)
        acc[mi][ni] = __builtin_amdgcn_mfma_scale_f32_16x16x128_f8f6f4(
            af[mi], bfz, acc[mi][ni], 0, 0, 0, 0x7f7f7f7f, 0, 0x7f7f7f7f);
    }
    __syncthreads();
  }

  // epilogue: exp(acc/32), bf16 tile + mirror, rowsums (direct + colsums)
  const float scale = 0.03125f;
  const bool mirror = (bi != bj);
  float colacc[4] = {0.f, 0.f, 0.f, 0.f};
#pragma unroll
  for (int mi = 0; mi < 4; ++mi) {
    float rs[4] = {0.f, 0.f, 0.f, 0.f};
#pragma unroll
    for (int ni = 0; ni < 4; ++ni)
#pragma unroll
      for (int reg = 0; reg < 4; ++reg) {
        float e = __expf(acc[mi][ni][reg] * scale);
        u16 h = f2bf(e);
        float f = bf2f(h);
        rs[reg] += f;
        if (mirror) colacc[ni] += f;
        stile[stile_off(wm + mi * 16 + q * 4 + reg, wn + ni * 16 + r)] = h;
      }
#pragma unroll
    for (int reg = 0; reg < 4; ++reg) {
      float v = rs[reg];
      v += __shfl_xor(v, 1);
      v += __shfl_xor(v, 2);
      v += __shfl_xor(v, 4);
      v += __shfl_xor(v, 8);
      if (r == 0)
        atomicAdd(&rowsum[mBase + wm + mi * 16 + q * 4 + reg], v);
    }
  }
  if (mirror) {
#pragma unroll
    for (int ni = 0; ni < 4; ++ni) {
      float v = colacc[ni];
      v += __shfl_xor(v, 16);
      v += __shfl_xor(v, 32);
      if (q == 0)
        atomicAdd(&rowsum[nBase + wn + ni * 16 + r], v);
    }
  }
  __syncthreads();
#pragma unroll
  for (int rnd = 0; rnd < 8; ++rnd) {
    int idx = rnd * 256 + tid;
    int ch = idx & 15, n = idx >> 4;
    short8 v = *(const short8*)(stile + n * 128 + ((ch ^ ((n >> 3) & 7)) << 3));
    *(short8*)(P + (size_t)(mBase + n) * 2048 + nBase + ch * 8) = v;
  }
  if (mirror) {
#pragma unroll
    for (int rnd = 0; rnd < 8; ++rnd) {
      int idx = rnd * 256 + tid;
      int ch = idx & 15, cc = idx >> 4;
      short8 v;
#pragma unroll
      for (int j = 0; j < 8; ++j) v[j] = (short)stile[stile_off(ch * 8 + j, cc)];
      *(short8*)(P + (size_t)(nBase + cc) * 2048 + mBase + ch * 8) = v;
    }
  }
}

// ============================================================================
// Kernel 3: O = (P @ c) / rowsum. A=P bf16 (K=2048), B=cT bf16, fp32 out.
// grid (batch=8, mblk*8+nblk=128): XCD = batch, n-fastest.
// ============================================================================
__global__ __launch_bounds__(256, 2)
void gemm_pv(const u16* __restrict__ A, const u16* __restrict__ B,
             float* __restrict__ Cf, const float* __restrict__ rowsum)
{
  __shared__ __align__(16) char smem[32768];
  u16* As = (u16*)smem;
  u16* Bs = As + 128 * 32;
  float* stf = (float*)smem;       // 64x128 f32 epilogue staging

  const int K = 2048, N = 1024;
  const int z = blockIdx.x;
  A += (size_t)z * 2048 * 2048;
  B += (size_t)z * 1024 * 2048;
  Cf += (size_t)z * 2048 * 1024;
  rowsum += (size_t)z * 2048;

  const int nBase = (blockIdx.y & 7) * 128;
  const int mBase = (blockIdx.y >> 3) * 128;

  const int tid  = threadIdx.x;
  const int lane = tid & 63;
  const int wave = tid >> 6;
  const int wm = (wave >> 1) * 64;
  const int wn = (wave & 1) * 64;
  const int q = lane >> 4;
  const int r = lane & 15;

  const int lo0 = tid * 16;
  const int lo1 = lo0 + 4096;
  const int row0 = lo0 >> 6, kc0 = (lo0 & 63) >> 1;
  const int row1 = lo1 >> 6, kc1 = (lo1 & 63) >> 1;

  const u16* a0 = A + (size_t)(mBase + row0) * K + kc0;
  const u16* a1 = A + (size_t)(mBase + row1) * K + kc1;
  const u16* b0 = B + (size_t)(nBase + row0) * K + kc0;
  const u16* b1 = B + (size_t)(nBase + row1) * K + kc1;

  f32x4 acc[4][4] = {};

  for (int k0 = 0; k0 < K; k0 += 32) {
    gload16(a0 + k0, (char*)As + lo0);
    gload16(a1 + k0, (char*)As + lo1);
    gload16(b0 + k0, (char*)Bs + lo0);
    gload16(b1 + k0, (char*)Bs + lo1);
    __syncthreads();
    short8 af[4], bfr[4];
#pragma unroll
    for (int t = 0; t < 4; ++t) {
      af[t]  = *(const short8*)(As + (wm + t * 16 + r) * 32 + q * 8);
      bfr[t] = *(const short8*)(Bs + (wn + t * 16 + r) * 32 + q * 8);
    }
#pragma unroll
    for (int mi = 0; mi < 4; ++mi)
#pragma unroll
      for (int ni = 0; ni < 4; ++ni)
        acc[mi][ni] = __builtin_amdgcn_mfma_f32_16x16x32_bf16(af[mi], bfr[ni], acc[mi][ni], 0, 0, 0);
    __syncthreads();
  }

  // normalize + fp32 store, staged through LDS in two 64-row phases
#pragma unroll
  for (int p = 0; p < 2; ++p) {
    if ((wave >> 1) == p) {
#pragma unroll
      for (int mi = 0; mi < 4; ++mi)
#pragma unroll
        for (int reg = 0; reg < 4; ++reg) {
          int lr = mi * 16 + q * 4 + reg;
          float inv = 1.0f / rowsum[mBase + wm + lr];
#pragma unroll
          for (int ni = 0; ni < 4; ++ni)
            stf[lr * 128 + wn + ni * 16 + r] = acc[mi][ni][reg] * inv;
        }
    }
    __syncthreads();
#pragma unroll
    for (int rnd = 0; rnd < 8; ++rnd) {
      int idx = rnd * 256 + tid;
      int n = idx >> 5, ch = idx & 31;
      float4 v = *(const float4*)(stf + n * 128 + ch * 4);
      *(float4*)(Cf + (size_t)(mBase + p * 64 + n) * N + nBase + ch * 4) = v;
    }
    __syncthreads();
  }
}

// ---------- launch ----------
// B=8, N=2048, E=O=1024
extern "C" void kernel_launch(void* const* d_in, const int* in_sizes, int n_in,
                              void* d_out, int out_size, void* d_ws, size_t ws_size,
                              hipStream_t stream) {
  const float* embd = (const float*)d_in[0];
  const float* W    = (const float*)d_in[1];
  const float* bias = (const float*)d_in[2];
  float* out = (float*)d_out;

  char* ws = (char*)d_ws;
  // lifetimes: cast -> linear -> scores -> pv
  u16* cT_b   = (u16*)(ws);                         // [0,32M)   W:linear R:pv
  u16* P_b    = (u16*)(ws + (32ull << 20));         // [32,96M)  W:scores R:pv
  u16* embd_b = (u16*)(ws + (32ull << 20));         // [32,64M)  alias P (dead before scores)
  u16* W_b    = (u16*)(ws + (64ull << 20));         // [64,66M)  alias P (dead before scores)
  u8*  c8     = (u8*)(ws + (96ull << 20));          // [96,112M) W:linear R:scores
  float* rowsum = (float*)(ws + (112ull << 20));    // 64 KB

  cast_all<<<17408, 256, 0, stream>>>(embd, W, embd_b, W_b);

  gemm_linear<<<dim3(8, 128, 1), 256, 0, stream>>>(embd_b, W_b, cT_b, c8, bias);

  hipMemsetAsync(rowsum, 0, 16384 * sizeof(float), stream);

  gemm_scores_fp8<<<dim3(8, 136, 1), 256, 0, stream>>>(c8, P_b, rowsum);

  gemm_pv<<<dim3(8, 128, 1), 256, 0, stream>>>(P_b, cT_b, out, rowsum);
}